// Round 9
// baseline (64.423 us; speedup 1.0000x reference)
//
#include <hip/hip_runtime.h>
#include <hip/hip_bf16.h>

// GraphAttentionLayer: N=16, Cin=64, T=512, V=64. One block per b=n*T+t.
// ONE-barrier structure exploiting own-wave LDS dependencies:
//   stage X (wave w writes rows 16w..16w+15; same rows its mm1 A-frags read
//   -> per-wave in-order DS pipe, no barrier)
//   mm1 (B-frags direct from prepped global Wt, L2-broadcast)
//   epilogue Y->LDS + f/g partials  -> __syncthreads() (the only barrier:
//   publishes Y rows + fpart/gpart + ml across waves)
//   softmax rows 16w..16w+15 -> P LDS (own rows)
//   mm2 (P B-frags = own rows, DS in-order; Y A-frags = all rows, post-barrier)

using bf16x8 = __attribute__((ext_vector_type(8))) short;
using f32x4  = __attribute__((ext_vector_type(4))) float;
typedef unsigned long long ull;

constexpr float ALPHA = 0.2f;
constexpr float LOG2E = 1.4426950408889634f;

__device__ __forceinline__ unsigned short f2bf(float f) {
    union { __hip_bfloat16 h; unsigned short s; } u;
    u.h = __float2bfloat16(f);
    return u.s;
}

// prep: Wt[v][u] = bf16(W[u][v]); maskbits[i] bit j = (Asum[i][j]>0)
__global__ void prep_kernel(const float* __restrict__ A,
                            const float* __restrict__ W,
                            unsigned short* __restrict__ Wt,
                            ull* __restrict__ mask) {
    const int tid = threadIdx.x;          // 256
    const int v = tid & 63, q = tid >> 6; // q=0..3
    #pragma unroll 4
    for (int m = 0; m < 16; ++m) {
        const int u = 16 * q + m;
        Wt[v * 64 + u] = f2bf(W[u * 64 + v]);
    }
    if (tid < 64) {
        ull m = 0;
        for (int j = 0; j < 64; ++j) {
            float s = A[tid * 64 + j] + A[4096 + tid * 64 + j] + A[8192 + tid * 64 + j];
            if (s > 0.f) m |= (1ull << j);
        }
        mask[tid] = m;
    }
}

__global__ __launch_bounds__(256, 7) void gat_kernel(
    const float* __restrict__ x,                 // (16,64,512,64) f32
    const float* __restrict__ a,                 // (128,)
    const unsigned short* __restrict__ Wt,       // (64,64) bf16, [v][u]
    const ull* __restrict__ maskbits,            // (64,)
    float* __restrict__ out)                     // (16,64,512,64) f32
{
    // stride-72 ushort rows (144B): row-parallel b128 reads <=2-way on banks.
    // LDS = 9216 + 9216 + 2048 + 512 = 20992 B -> 7 blocks/CU.
    __shared__ unsigned short XbYb[64 * 72];  // X (mm1 A) then Y (mm2 A)
    __shared__ unsigned short Pb[64 * 72];    // P (mm2 B^T)
    __shared__ float fpart[4][64];
    __shared__ float gpart[4][64];
    __shared__ ull ml[64];

    const int tid = threadIdx.x;
    const int b = blockIdx.x;
    const int n = b >> 9, t = b & 511;
    const int w = tid >> 6, lane = tid & 63;
    const int fr = lane & 15, hi = lane >> 4;
    const int fk = hi * 8;

    if (tid < 64) ml[tid] = maskbits[tid];

    // ---- stage X (fp32 -> bf16): wave w writes its OWN rows 16w..16w+15 ----
    {
        const int c = tid >> 2, q = tid & 3;   // c = 16w + (lane>>2)
        const float* xp = x + (size_t)n * 2097152 + (size_t)c * 32768
                            + (size_t)t * 64 + q * 16;
        float4 v0 = ((const float4*)xp)[0];
        float4 v1 = ((const float4*)xp)[1];
        float4 v2 = ((const float4*)xp)[2];
        float4 v3 = ((const float4*)xp)[3];
        union { bf16x8 v; unsigned short s[8]; } u0, u1;
        u0.s[0]=f2bf(v0.x); u0.s[1]=f2bf(v0.y); u0.s[2]=f2bf(v0.z); u0.s[3]=f2bf(v0.w);
        u0.s[4]=f2bf(v1.x); u0.s[5]=f2bf(v1.y); u0.s[6]=f2bf(v1.z); u0.s[7]=f2bf(v1.w);
        u1.s[0]=f2bf(v2.x); u1.s[1]=f2bf(v2.y); u1.s[2]=f2bf(v2.z); u1.s[3]=f2bf(v2.w);
        u1.s[4]=f2bf(v3.x); u1.s[5]=f2bf(v3.y); u1.s[6]=f2bf(v3.z); u1.s[7]=f2bf(v3.w);
        *(bf16x8*)&XbYb[c * 72 + q * 16]     = u0.v;
        *(bf16x8*)&XbYb[c * 72 + q * 16 + 8] = u1.v;
    }
    // NO barrier: mm1 A-frags read rows 16w+fr — written by this wave;
    // per-wave DS ops execute in issue order.

    // ---- mm1: Y = X @ W; B-frags straight from global Wt (L2-broadcast) ----
    {
        f32x4 acc[4] = {{0,0,0,0},{0,0,0,0},{0,0,0,0},{0,0,0,0}};
        #pragma unroll
        for (int kc = 0; kc < 2; ++kc) {
            bf16x8 af = *(const bf16x8*)&XbYb[(16 * w + fr) * 72 + 32 * kc + fk];
            #pragma unroll
            for (int cb = 0; cb < 4; ++cb) {
                bf16x8 bfr = *(const bf16x8*)&Wt[(16 * cb + fr) * 64 + 32 * kc + fk];
                acc[cb] = __builtin_amdgcn_mfma_f32_16x16x32_bf16(af, bfr, acc[cb], 0, 0, 0);
            }
        }
        // epilogue: Y -> LDS bf16 (own rows), f/g partials (log2e pre-scaled)
        const float4 a1v = *(const float4*)&a[16 * w + 4 * hi];
        const float4 a2v = *(const float4*)&a[64 + 16 * w + 4 * hi];
        #pragma unroll
        for (int cb = 0; cb < 4; ++cb) {
            #pragma unroll
            for (int r = 0; r < 4; ++r)
                XbYb[(16 * w + 4 * hi + r) * 72 + 16 * cb + fr] = f2bf(acc[cb][r]);
            float F = acc[cb][0]*a1v.x + acc[cb][1]*a1v.y + acc[cb][2]*a1v.z + acc[cb][3]*a1v.w;
            float G = acc[cb][0]*a2v.x + acc[cb][1]*a2v.y + acc[cb][2]*a2v.z + acc[cb][3]*a2v.w;
            F += __shfl_xor(F, 16, 64); F += __shfl_xor(F, 32, 64);
            G += __shfl_xor(G, 16, 64); G += __shfl_xor(G, 32, 64);
            if (lane < 16) {
                fpart[w][16 * cb + lane] = F * LOG2E;
                gpart[w][16 * cb + lane] = G * LOG2E;
            }
        }
    }
    __syncthreads();   // the ONLY barrier: publishes Y rows, fpart/gpart, ml

    // ---- softmax rows 16w..16w+15 (unnormalized, base-2) ----
    {
        const float gj = (gpart[0][lane] + gpart[1][lane]) + (gpart[2][lane] + gpart[3][lane]);
        const int myrow = 16 * w + fr;
        const float fvalL = (fpart[0][myrow] + fpart[1][myrow])
                          + (fpart[2][myrow] + fpart[3][myrow]);
        #pragma unroll 4
        for (int k = 0; k < 16; ++k) {
            const int i = 16 * w + k;
            const float fi = __shfl(fvalL, k, 64);   // lane k holds row 16w+k
            const ull mi = ml[i];
            const float s0 = fi + gj;
            const float e = fmaxf(s0, ALPHA * s0);   // lrelu (log2e>0 commutes)
            const float p = (mi == 0ull) ? 1.0f
                          : (((mi >> lane) & 1ull) ? exp2f(e) : 0.0f);
            Pb[i * 72 + lane] = f2bf(p);
        }
    }
    // NO barrier: mm2 P-frags read rows 16w+fr — own-wave writes, DS in-order.

    // ---- mm2: out[c,v] = (sum_j Y[c,j]P[v,j]) * rcp(S_v); S via ones-MFMA ----
    {
        union { bf16x8 v; unsigned short s[8]; } ones;
        #pragma unroll
        for (int j = 0; j < 8; ++j) ones.s[j] = 0x3f80;   // bf16 1.0
        bf16x8 pb0 = *(const bf16x8*)&Pb[(16 * w + fr) * 72 + fk];
        bf16x8 pb1 = *(const bf16x8*)&Pb[(16 * w + fr) * 72 + 32 + fk];
        f32x4 accS = {0, 0, 0, 0};
        accS = __builtin_amdgcn_mfma_f32_16x16x32_bf16(ones.v, pb0, accS, 0, 0, 0);
        accS = __builtin_amdgcn_mfma_f32_16x16x32_bf16(ones.v, pb1, accS, 0, 0, 0);
        f32x4 acc2[4] = {{0,0,0,0},{0,0,0,0},{0,0,0,0},{0,0,0,0}};
        #pragma unroll
        for (int rb = 0; rb < 4; ++rb) {
            bf16x8 y0 = *(const bf16x8*)&XbYb[(16 * rb + fr) * 72 + fk];
            bf16x8 y1 = *(const bf16x8*)&XbYb[(16 * rb + fr) * 72 + 32 + fk];
            acc2[rb] = __builtin_amdgcn_mfma_f32_16x16x32_bf16(y0, pb0, acc2[rb], 0, 0, 0);
            acc2[rb] = __builtin_amdgcn_mfma_f32_16x16x32_bf16(y1, pb1, acc2[rb], 0, 0, 0);
        }
        const float rs = __builtin_amdgcn_rcpf(accS[0]);   // S_v, v = 16w+fr
        float* op = out + (size_t)n * 2097152 + (size_t)t * 64 + 16 * w + fr;
        #pragma unroll
        for (int rb = 0; rb < 4; ++rb)
            #pragma unroll
            for (int r = 0; r < 4; ++r)
                op[(size_t)(16 * rb + 4 * hi + r) * 32768] = acc2[rb][r] * rs;
    }
}

extern "C" void kernel_launch(void* const* d_in, const int* in_sizes, int n_in,
                              void* d_out, int out_size, void* d_ws, size_t ws_size,
                              hipStream_t stream) {
    const float* x = (const float*)d_in[0];
    const float* A = (const float*)d_in[1];
    const float* W = (const float*)d_in[2];
    const float* a = (const float*)d_in[3];
    float* out = (float*)d_out;
    unsigned short* Wt = (unsigned short*)d_ws;     // 8192 B
    ull* mask = (ull*)((char*)d_ws + 8192);         // 512 B

    prep_kernel<<<1, 256, 0, stream>>>(A, W, Wt, mask);
    gat_kernel<<<16 * 512, 256, 0, stream>>>(x, a, Wt, mask, out);
}